// Round 7
// baseline (1836.006 us; speedup 1.0000x reference)
//
#include <hip/hip_runtime.h>
#include <hip/hip_bf16.h>
#include <math.h>

#define NPTS 2048
#define NB 16
#define KNN 20
#define GP 40   // LDS pitch (bf16) for final-GEMM staging buffers

typedef __attribute__((ext_vector_type(8))) short bf16x8;
typedef __attribute__((ext_vector_type(4))) float f32x4;

__device__ __forceinline__ float lrelu(float v) { return fmaxf(v, 0.2f * v); }

// split two floats into packed bf16 hi pair + packed bf16 lo (residual) pair
__device__ __forceinline__ void split2(float a, float b, unsigned& hp, unsigned& lp) {
    float2 f2; f2.x = a; f2.y = b;
    __hip_bfloat162 h2 = __float22bfloat162_rn(f2);
    unsigned hb; __builtin_memcpy(&hb, &h2, 4);
    float la = a - __uint_as_float(hb << 16);
    float lb = b - __uint_as_float(hb & 0xFFFF0000u);
    float2 l2; l2.x = la; l2.y = lb;
    __hip_bfloat162 k2 = __float22bfloat162_rn(l2);
    unsigned lb2; __builtin_memcpy(&lb2, &k2, 4);
    hp = hb; lp = lb2;
}

// ---- transpose x [B,N,3] -> h0 [B,3,N]
__global__ void transpose_kernel(const float* __restrict__ x, float* __restrict__ h0) {
    int t = blockIdx.x * blockDim.x + threadIdx.x;
    if (t >= NB * NPTS) return;
    int b = t / NPTS, n = t % NPTS;
    const float* src = x + (size_t)t * 3;
    float* dst = h0 + (size_t)b * 3 * NPTS + n;
    dst[0]        = src[0];
    dst[NPTS]     = src[1];
    dst[2 * NPTS] = src[2];
}

// ---- split layer input [b][c][m] fp32 -> xh/xl [b][m][CP] bf16 (transposed), + sq
__global__ __launch_bounds__(256) void xsplit_kernel(const float* __restrict__ in, long bstride,
                                                     int C, int CP,
                                                     unsigned short* __restrict__ xh,
                                                     unsigned short* __restrict__ xl,
                                                     float* __restrict__ sq) {
    int t = blockIdx.x * 256 + threadIdx.x;      // b*N + m
    int b = t >> 11;
    int m = t & 2047;
    const float* p = in + (size_t)b * bstride + m;
    unsigned short* ph = xh + (size_t)t * CP;
    unsigned short* pl = xl + (size_t)t * CP;
    float s = 0.f;
    for (int c0 = 0; c0 < CP; c0 += 8) {
        float v[8];
        unsigned hw[4], lw[4];
#pragma unroll
        for (int j = 0; j < 8; ++j) {
            int c = c0 + j;
            v[j] = (c < C) ? p[(size_t)c * NPTS] : 0.f;
            s = fmaf(v[j], v[j], s);
        }
#pragma unroll
        for (int pp = 0; pp < 4; ++pp) split2(v[2 * pp], v[2 * pp + 1], hw[pp], lw[pp]);
        *(uint4*)(ph + c0) = make_uint4(hw[0], hw[1], hw[2], hw[3]);
        *(uint4*)(pl + c0) = make_uint4(lw[0], lw[1], lw[2], lw[3]);
    }
    sq[t] = s;
}

// ---- fused kNN v2: block = 16 waves, 16 query rows (one wave per row for select).
// MFMA fragments loaded directly from global (pre-transposed bf16 hi/lo). LDS only
// holds the 16x2050 fp32 score strip. Select = ballot bisection for exact top-20.
// __launch_bounds__(1024, 1): hipcc's 2nd arg is min BLOCKS/CU (CUDA-style) —
// evidence: r5 (1024,4) -> VGPR 32 = 512/(4*4waves/EU); r6 default -> 48 (2-block
// heuristic, 64 cap) -> key[32] spilled to scratch -> 8.6 GB scratch reloads =
// the 476us. (1024,1) -> cap 128, no spill. LDS (131 KB) forces 1 block/CU anyway.
template<int CP>
__global__ __launch_bounds__(1024, 1) void knn_fused2(const unsigned short* __restrict__ xh,
                                                      const unsigned short* __restrict__ xl,
                                                      const float* __restrict__ sq,
                                                      int* __restrict__ idx) {
    extern __shared__ __align__(16) float scores[];   // [16][2050]
    constexpr int KS = CP / 32;

    int g = blockIdx.x;
    int j8 = g & 7, s = g >> 3;          // XCD j8 owns batches 2*j8, 2*j8+1
    int b = 2 * j8 + (s & 1);
    int nt = s >> 1;                     // 0..127
    int n0 = nt * 16;

    int tid = threadIdx.x;
    int w = tid >> 6, lane = tid & 63;
    int l15 = lane & 15, q = lane >> 4;

    const unsigned short* xhb = xh + (size_t)b * NPTS * CP;
    const unsigned short* xlb = xl + (size_t)b * NPTS * CP;

    // A fragments (query rows n0..n0+15): A[m=l15][k=q*8+jj]
    bf16x8 ah[KS], al[KS];
#pragma unroll
    for (int ks = 0; ks < KS; ++ks) {
        ah[ks] = *(const bf16x8*)&xhb[(size_t)(n0 + l15) * CP + ks * 32 + q * 8];
        al[ks] = *(const bf16x8*)&xlb[(size_t)(n0 + l15) * CP + ks * 32 + q * 8];
    }

    // compute: wave w covers m in [w*128, w*128+128)
    int mbase = w * 128;
#pragma unroll 2
    for (int c16 = 0; c16 < 8; ++c16) {
        int m0 = mbase + c16 * 16;
        f32x4 acc = (f32x4)0.f;
#pragma unroll
        for (int ks = 0; ks < KS; ++ks) {
            bf16x8 bh = *(const bf16x8*)&xhb[(size_t)(m0 + l15) * CP + ks * 32 + q * 8];
            bf16x8 bl = *(const bf16x8*)&xlb[(size_t)(m0 + l15) * CP + ks * 32 + q * 8];
            acc = __builtin_amdgcn_mfma_f32_16x16x32_bf16(ah[ks], bh, acc, 0, 0, 0);
            acc = __builtin_amdgcn_mfma_f32_16x16x32_bf16(ah[ks], bl, acc, 0, 0, 0);
            acc = __builtin_amdgcn_mfma_f32_16x16x32_bf16(al[ks], bh, acc, 0, 0, 0);
        }
        float sv = sq[b * NPTS + m0 + l15];
#pragma unroll
        for (int r = 0; r < 4; ++r)
            scores[(q * 4 + r) * 2050 + m0 + l15] = 2.f * acc[r] - sv;
    }
    __syncthreads();

    // ---- select: wave w owns query row w. keys = sortable-uint of scores.
    unsigned key[32];
#pragma unroll
    for (int u = 0; u < 32; ++u) {
        unsigned bits = __float_as_uint(scores[w * 2050 + lane + 64 * u]);
        key[u] = (bits & 0x80000000u) ? ~bits : (bits | 0x80000000u);
    }

    // bisection: largest t with count(key >= t) >= 20  ->  t = 20th-largest key
    unsigned t = 0;
    for (int bit = 31; bit >= 0; --bit) {
        unsigned cand = t | (1u << bit);
        int cnt = 0;
#pragma unroll
        for (int u = 0; u < 32; ++u)
            cnt += __popcll(__ballot(key[u] >= cand));
        if (cnt >= KNN) t = cand;
    }

    int* out = idx + ((size_t)b * NPTS + n0 + w) * KNN;
    unsigned long long below = (lane == 63) ? 0x7FFFFFFFFFFFFFFFull
                                            : ((1ull << lane) - 1);
    int base = 0;
    // emit strictly-greater (count < 20 guaranteed)
#pragma unroll
    for (int u = 0; u < 32; ++u) {
        unsigned long long mk = __ballot(key[u] > t);
        if (key[u] > t) out[base + __popcll(mk & below)] = lane + 64 * u;
        base += __popcll(mk);
    }
    // emit ties == t, lowest m index first (u ascending, lane-prefix ascending)
#pragma unroll
    for (int u = 0; u < 32; ++u) {
        if (base >= KNN) break;
        unsigned long long mk = __ballot(key[u] == t);
        int p = base + __popcll(mk & below);
        if ((key[u] == t) && p < KNN) out[p] = lane + 64 * u;
        base += __popcll(mk);
    }
}

// ---- Wa[c][o] = W[o][c]; Wd[c][o] = W[o][C+c] - W[o][c]
__global__ void prep_w_kernel(const float* __restrict__ W, int C, int O,
                              float* __restrict__ Wa, float* __restrict__ Wd) {
    int t = blockIdx.x * blockDim.x + threadIdx.x;
    if (t >= C * O) return;
    int c = t / O, o = t % O;
    float a = W[o * 2 * C + c];
    float d = W[o * 2 * C + C + c] - a;
    Wa[c * O + o] = a;
    Wd[c * O + o] = d;
}

// ---- y[b,o,m] = Wa@x_m ; base[b,off+o,n] = Wd@x_n + bias
__global__ __launch_bounds__(256) void edge_mm_kernel(const float* __restrict__ xin, long bstride,
                                                      int C, int O,
                                                      const float* __restrict__ Wa,
                                                      const float* __restrict__ Wd,
                                                      const float* __restrict__ bias,
                                                      float* __restrict__ y,
                                                      float* __restrict__ base, long base_bstride) {
    int m = blockIdx.x * 256 + threadIdx.x;
    int ngrp = O >> 3;
    int og = blockIdx.y % ngrp, b = blockIdx.y / ngrp;
    int o0 = og * 8;
    const float* xb = xin + (size_t)b * bstride + m;
    float a1[8], a2[8];
#pragma unroll
    for (int i = 0; i < 8; ++i) { a1[i] = 0.f; a2[i] = 0.f; }
#pragma unroll 2
    for (int c = 0; c < C; ++c) {
        float h = xb[(size_t)c * NPTS];
        const float* wa = Wa + c * O + o0;
        const float* wd = Wd + c * O + o0;
#pragma unroll
        for (int i = 0; i < 8; ++i) {
            a1[i] = fmaf(wa[i], h, a1[i]);
            a2[i] = fmaf(wd[i], h, a2[i]);
        }
    }
#pragma unroll
    for (int i = 0; i < 8; ++i) {
        y[((size_t)b * O + o0 + i) * NPTS + m] = a1[i];
        base[(size_t)b * base_bstride + (size_t)(o0 + i) * NPTS + m] = a2[i] + bias[o0 + i];
    }
}

// ---- feat[b,off+o,n] = lrelu( max_j y[b,o,idx[b,n,j]] + base )
__global__ __launch_bounds__(256) void gather_max_kernel(const float* __restrict__ y, int O,
                                                         const int* __restrict__ idx,
                                                         float* __restrict__ feat_slice,
                                                         long bstride) {
    __shared__ float yrow[NPTS];
    int o = blockIdx.x, b = blockIdx.y;
    const float* ysrc = y + ((size_t)b * O + o) * NPTS;
    for (int m = threadIdx.x; m < NPTS; m += 256) yrow[m] = ysrc[m];
    __syncthreads();
    float* fs = feat_slice + (size_t)b * bstride + (size_t)o * NPTS;
    const int* ib = idx + (size_t)b * NPTS * KNN;
    for (int s = 0; s < 8; ++s) {
        int n = threadIdx.x + 256 * s;
        const int* ip = ib + n * KNN;
        float mx = -INFINITY;
#pragma unroll
        for (int j = 0; j < KNN; ++j) mx = fmaxf(mx, yrow[ip[j]]);
        fs[n] = lrelu(mx + fs[n]);
    }
}

// ---- split Wf (fp32 [1024][512]) into packed bf16 hi/lo
__global__ void wf_split_kernel(const float* __restrict__ Wf,
                                unsigned* __restrict__ Wfh, unsigned* __restrict__ Wfl) {
    int t = blockIdx.x * 256 + threadIdx.x;
    if (t >= 262144) return;
    unsigned h, l;
    split2(Wf[2 * t], Wf[2 * t + 1], h, l);
    Wfh[t] = h; Wfl[t] = l;
}

// ---- final GEMM via bf16 hi/lo split MFMA, max-over-n epilogue, XCD-aware decode
__global__ __launch_bounds__(256) void final_gemm_mfma(
    const float* __restrict__ feat,
    const unsigned short* __restrict__ Wfh,
    const unsigned short* __restrict__ Wfl,
    float* __restrict__ pmax) {
    __shared__ __align__(16) unsigned short Ah[128 * GP];
    __shared__ __align__(16) unsigned short Al[128 * GP];
    __shared__ __align__(16) unsigned short Bh[128 * GP];
    __shared__ __align__(16) unsigned short Bl[128 * GP];

    int g = blockIdx.x;
    int j = g & 7, s = g >> 3;
    int b = 2 * j + (s >> 7);
    int r7 = s & 127;
    int nt = r7 >> 3, ot = r7 & 7;

    int o0 = ot * 128, n0 = nt * 128;
    int tid = threadIdx.x;
    int lane = tid & 63, w = tid >> 6;
    int wm = w & 1, wn = w >> 1;
    int l15 = lane & 15, q = lane >> 4;

    f32x4 acc[4][4];
#pragma unroll
    for (int mi = 0; mi < 4; ++mi)
#pragma unroll
        for (int ni = 0; ni < 4; ++ni) acc[mi][ni] = (f32x4)0.f;

    const float* fb = feat + (size_t)b * 512 * NPTS;
    int bn = tid & 127, kh = tid >> 7;

    for (int c0 = 0; c0 < 512; c0 += 32) {
#pragma unroll
        for (int p = 0; p < 2; ++p) {
            int e = p * 256 + tid;
            int rr = e >> 2, qq = e & 3;
            size_t go = (size_t)(o0 + rr) * 512 + c0 + qq * 8;
            *(uint4*)&Ah[rr * GP + qq * 8] = *(const uint4*)(Wfh + go);
            *(uint4*)&Al[rr * GP + qq * 8] = *(const uint4*)(Wfl + go);
        }
        {
            const float* src = fb + (size_t)(c0 + kh * 16) * NPTS + n0 + bn;
            float v[16];
#pragma unroll
            for (int jj = 0; jj < 16; ++jj) v[jj] = src[(size_t)jj * NPTS];
            unsigned hw[8], lw[8];
#pragma unroll
            for (int p = 0; p < 8; ++p) split2(v[2 * p], v[2 * p + 1], hw[p], lw[p]);
            unsigned short* bh = &Bh[bn * GP + kh * 16];
            unsigned short* bl = &Bl[bn * GP + kh * 16];
            *(uint4*)(bh)     = make_uint4(hw[0], hw[1], hw[2], hw[3]);
            *(uint4*)(bh + 8) = make_uint4(hw[4], hw[5], hw[6], hw[7]);
            *(uint4*)(bl)     = make_uint4(lw[0], lw[1], lw[2], lw[3]);
            *(uint4*)(bl + 8) = make_uint4(lw[4], lw[5], lw[6], lw[7]);
        }
        __syncthreads();

        bf16x8 bhf[4], blf[4];
#pragma unroll
        for (int ni = 0; ni < 4; ++ni) {
            int row = wn * 64 + ni * 16 + l15;
            bhf[ni] = *(const bf16x8*)&Bh[row * GP + q * 8];
            blf[ni] = *(const bf16x8*)&Bl[row * GP + q * 8];
        }
#pragma unroll
        for (int mi = 0; mi < 4; ++mi) {
            int row = wm * 64 + mi * 16 + l15;
            bf16x8 ah = *(const bf16x8*)&Ah[row * GP + q * 8];
            bf16x8 al = *(const bf16x8*)&Al[row * GP + q * 8];
#pragma unroll
            for (int ni = 0; ni < 4; ++ni) {
                acc[mi][ni] = __builtin_amdgcn_mfma_f32_16x16x32_bf16(ah, bhf[ni], acc[mi][ni], 0, 0, 0);
                acc[mi][ni] = __builtin_amdgcn_mfma_f32_16x16x32_bf16(ah, blf[ni], acc[mi][ni], 0, 0, 0);
                acc[mi][ni] = __builtin_amdgcn_mfma_f32_16x16x32_bf16(al, bhf[ni], acc[mi][ni], 0, 0, 0);
            }
        }
        __syncthreads();
    }

    int slot = nt * 2 + wn;
#pragma unroll
    for (int mi = 0; mi < 4; ++mi) {
        float m4[4];
#pragma unroll
        for (int rr = 0; rr < 4; ++rr) {
            float m = acc[mi][0][rr];
            m = fmaxf(m, acc[mi][1][rr]);
            m = fmaxf(m, acc[mi][2][rr]);
            m = fmaxf(m, acc[mi][3][rr]);
            m4[rr] = m;
        }
#pragma unroll
        for (int off = 1; off < 16; off <<= 1) {
#pragma unroll
            for (int rr = 0; rr < 4; ++rr)
                m4[rr] = fmaxf(m4[rr], __shfl_xor(m4[rr], off, 16));
        }
        if (l15 == 0) {
            int mbase = o0 + wm * 64 + mi * 16 + q * 4;
#pragma unroll
            for (int rr = 0; rr < 4; ++rr)
                pmax[((size_t)b * 1024 + mbase + rr) * 32 + slot] = m4[rr];
        }
    }
}

__global__ void final_reduce_kernel(const float* __restrict__ pmax,
                                    const float* __restrict__ bf,
                                    float* __restrict__ out) {
    int t = blockIdx.x * blockDim.x + threadIdx.x;
    if (t >= NB * 1024) return;
    const float* p = pmax + (size_t)t * 32;
    float m = p[0];
#pragma unroll
    for (int i = 1; i < 32; ++i) m = fmaxf(m, p[i]);
    out[t] = lrelu(m + bf[t & 1023]);
}

extern "C" void kernel_launch(void* const* d_in, const int* in_sizes, int n_in,
                              void* d_out, int out_size, void* d_ws, size_t ws_size,
                              hipStream_t stream) {
    const float* x  = (const float*)d_in[0];
    const float* W[4]  = {(const float*)d_in[1], (const float*)d_in[3],
                          (const float*)d_in[5], (const float*)d_in[7]};
    const float* bb[4] = {(const float*)d_in[2], (const float*)d_in[4],
                          (const float*)d_in[6], (const float*)d_in[8]};
    const float* Wf = (const float*)d_in[9];
    const float* bf = (const float*)d_in[10];
    float* out = (float*)d_out;

    float* ws   = (float*)d_ws;
    float* h0   = ws;                       // B*3*N      = 98304
    float* sq   = h0 + 98304;               // B*N        = 32768
    int*   idx  = (int*)(sq + 32768);       // B*N*20     = 655360
    float* y    = (float*)(idx + 655360);   // B*256*N    = 8388608 (multi-use)
    float* feat = y + 8388608;              // B*512*N    = 16777216
    float* Wa   = feat + 16777216 + 262144; // 128*256    = 32768
    float* Wd   = Wa + 32768;               // 128*256    = 32768

    // overlays in the y region (dead at the relevant times):
    unsigned short* xh = (unsigned short*)y;         // 16*2048*CP ushorts (<=8.4 MB)
    unsigned short* xl = xh + (size_t)16 * 2048 * 128;
    unsigned* Wfh = (unsigned*)y;                    // after layer loop
    unsigned* Wfl = (unsigned*)(y + 262144);
    float*    pmax = y + 524288;                     // 16*1024*32 floats

    transpose_kernel<<<128, 256, 0, stream>>>(x, h0);

    const int  Cs[4]   = {3, 64, 64, 128};
    const int  Os[4]   = {64, 64, 128, 256};
    const int  offs[4] = {0, 64, 128, 256};

    for (int l = 0; l < 4; ++l) {
        const float* in = (l == 0) ? h0 : feat + (size_t)offs[l - 1] * NPTS;
        long bstr = (l == 0) ? (long)3 * NPTS : (long)512 * NPTS;
        int C = Cs[l], O = Os[l];
        int CP = (l == 0) ? 32 : C;

        xsplit_kernel<<<128, 256, 0, stream>>>(in, bstr, C, CP, xh, xl, sq);

        size_t smem = (size_t)16 * 2050 * 4;   // 131200 B
        if (CP == 32)      knn_fused2<32> <<<2048, 1024, smem, stream>>>(xh, xl, sq, idx);
        else if (CP == 64) knn_fused2<64> <<<2048, 1024, smem, stream>>>(xh, xl, sq, idx);
        else               knn_fused2<128><<<2048, 1024, smem, stream>>>(xh, xl, sq, idx);

        prep_w_kernel<<<(C * O + 255) / 256, 256, 0, stream>>>(W[l], C, O, Wa, Wd);

        float* fslice = feat + (size_t)offs[l] * NPTS;
        edge_mm_kernel<<<dim3(NPTS / 256, NB * (O >> 3)), 256, 0, stream>>>(
            in, bstr, C, O, Wa, Wd, bb[l], y, fslice, (long)512 * NPTS);

        gather_max_kernel<<<dim3(O, NB), 256, 0, stream>>>(y, O, idx, fslice, (long)512 * NPTS);
    }

    wf_split_kernel<<<1024, 256, 0, stream>>>(Wf, Wfh, Wfl);
    final_gemm_mfma<<<2048, 256, 0, stream>>>(
        feat, (const unsigned short*)Wfh, (const unsigned short*)Wfl, pmax);
    final_reduce_kernel<<<64, 256, 0, stream>>>(pmax, bf, out);
}